// Round 21
// baseline (19.934 us; speedup 1.0000x reference)
//
#include <hip/hip_runtime.h>

// Fused NeRF: PE (4 freq) + MLP 27->32->1 via 32x32x16 bf16 MFMA (K=28->2x16).
// R20 = R16 (best passing: 17.91us) + the two VALUE-IDENTICAL micro-cuts from
// R19 (float3 dwordx3 loads, f32x8 packed relu); cross-half reduce reverted
// to the known-good __shfl_xor(s,32) (R19's permlane32_swap select was wrong).

#define NPTS  2097152
#define BLOCK 512
#define TILES 4
#define NBLK  (NPTS / (64 * (BLOCK / 64) * TILES))   // 1024

typedef __bf16 bf16x8 __attribute__((ext_vector_type(8)));
typedef __bf16 bf16x2 __attribute__((ext_vector_type(2)));
typedef float  f32x8  __attribute__((ext_vector_type(8)));
typedef float  f32x16 __attribute__((ext_vector_type(16)));
typedef float  f32x2  __attribute__((ext_vector_type(2)));
typedef unsigned int u32;
typedef u32 u32x4 __attribute__((ext_vector_type(4)));

__device__ __forceinline__ u32 pk_sc(float ang /*revolutions*/) {
    const float a = __builtin_amdgcn_fractf(ang);
    f32x2 sc;
    sc[0] = __builtin_amdgcn_sinf(a);
    sc[1] = __builtin_amdgcn_cosf(a);
    return __builtin_bit_cast(u32, __builtin_convertvector(sc, bf16x2));
}

__global__ __launch_bounds__(BLOCK, 4) void nerf_r20(
    const float* __restrict__ x,
    const float* __restrict__ W1,
    const float* __restrict__ b1,
    const float* __restrict__ W2,
    const float* __restrict__ b2,
    float* __restrict__ out)
{
    const int tid  = threadIdx.x;
    const int wave = tid >> 6;
    const int lane = tid & 63;
    const int h    = lane >> 5;   // k-half: bands {h, 2+h}
    const int col  = lane & 31;   // point-in-group / hidden j (A operand)

    const float INV2PI = 0.15915494309189535f;
    const float FgA = (h ? 10.0793684f : 1.0f)         * INV2PI;
    const float FgB = (h ? 1024.0f     : 101.5936673f) * INV2PI;
    const float bias2 = b2[0];
    const f32x16 Z = {};

    // ---- layer-1 A fragments gathered from global (L1-resident) ----
    bf16x8 af1, af2;
    {
        f32x8 t1, t2;
        #pragma unroll
        for (int m = 0; m < 3; ++m) {
            t1[2 * m]     = W1[(3  + 6 * h + m) * 32 + col];
            t1[2 * m + 1] = W1[(6  + 6 * h + m) * 32 + col];
            t2[2 * m]     = W1[(15 + 6 * h + m) * 32 + col];
            t2[2 * m + 1] = W1[(18 + 6 * h + m) * 32 + col];
        }
        t1[6] = h ? W1[2 * 32 + col] : W1[0 * 32 + col];
        t1[7] = h ? b1[col]          : W1[1 * 32 + col];   // bias | x1-row
        t2[6] = 0.0f; t2[7] = 0.0f;
        af1 = __builtin_convertvector(t1, bf16x8);
        af2 = __builtin_convertvector(t2, bf16x8);
    }
    // layer-2 weights for lane's 16 C/D rows (pairs for pk_fma)
    f32x2 w2p[8];
    #pragma unroll
    for (int m = 0; m < 8; ++m) {
        const int r0 = 8 * (m >> 1) + 4 * h + 2 * (m & 1);
        w2p[m][0] = W2[r0];
        w2p[m][1] = W2[r0 + 1];
    }

    const int tbase = blockIdx.x * ((BLOCK / 64) * TILES) + wave * TILES;
    const float3* xb3 = (const float3*)(x + (size_t)tbase * 192) + col;
    float* ob = out + (size_t)tbase * 64 + lane;

    #pragma unroll
    for (int t = 0; t < TILES; ++t) {
        float S[2];
        #pragma unroll
        for (int gr = 0; gr < 2; ++gr) {
            // one dwordx3 load: point 64t + 32gr + col (R13-proven pattern)
            const float3 P = xb3[t * 64 + gr * 32];
            const float x0 = P.x, x1 = P.y, x2 = P.z;

            u32x4 u1, u2;
            u1[0] = pk_sc(x0 * FgA);
            u1[1] = pk_sc(x1 * FgA);
            u1[2] = pk_sc(x2 * FgA);
            f32x2 ex;
            ex[0] = h ? x2 : x0;
            ex[1] = h ? 1.0f : x1;     // bias multiplier lives in h=1
            u1[3] = __builtin_bit_cast(u32, __builtin_convertvector(ex, bf16x2));
            u2[0] = pk_sc(x0 * FgB);
            u2[1] = pk_sc(x1 * FgB);
            u2[2] = pk_sc(x2 * FgB);
            u2[3] = 0u;
            const bf16x8 B1 = __builtin_bit_cast(bf16x8, u1);
            const bf16x8 B2 = __builtin_bit_cast(bf16x8, u2);

            // layer 1: 2 chained 32x32x16 MFMAs -> 32 hidden x 32 points
            f32x16 acc = __builtin_amdgcn_mfma_f32_32x32x16_bf16(af1, B1, Z, 0, 0, 0);
            acc = __builtin_amdgcn_mfma_f32_32x32x16_bf16(af2, B2, acc, 0, 0, 0);

            // layer 2: packed relu + pk_fma over lane's 16 rows
            f32x8 lo, hi;
            #pragma unroll
            for (int i = 0; i < 8; ++i) { lo[i] = acc[i]; hi[i] = acc[8 + i]; }
            const f32x8 z8 = {};
            lo = __builtin_elementwise_max(lo, z8);
            hi = __builtin_elementwise_max(hi, z8);
            f32x2 ps = {0.0f, 0.0f};
            #pragma unroll
            for (int m = 0; m < 4; ++m) {
                f32x2 a = {lo[2 * m], lo[2 * m + 1]};
                f32x2 b = {hi[2 * m], hi[2 * m + 1]};
                ps = ps + a * w2p[m];
                ps = ps + b * w2p[4 + m];
            }
            float s = ps[0] + ps[1];
            s += __shfl_xor(s, 32, 64);   // combine k-halves (known-good)
            S[gr] = s;
        }
        // lane (h,col) stores point 32h+col of the tile
        const float v = h ? S[1] : S[0];
        ob[t * 64] = fmaxf(v + bias2, 0.0f);
    }
}

extern "C" void kernel_launch(void* const* d_in, const int* in_sizes, int n_in,
                              void* d_out, int out_size, void* d_ws, size_t ws_size,
                              hipStream_t stream) {
    const float* x  = (const float*)d_in[0];
    const float* W1 = (const float*)d_in[1];
    const float* b1 = (const float*)d_in[2];
    const float* W2 = (const float*)d_in[3];
    const float* b2 = (const float*)d_in[4];
    float* out = (float*)d_out;

    nerf_r20<<<NBLK, BLOCK, 0, stream>>>(x, W1, b1, W2, b2, out);
}

// Round 22
// 17.817 us; speedup vs baseline: 1.1188x; 1.1188x over previous
//
#include <hip/hip_runtime.h>

// Fused NeRF: PE (4 freq) + MLP 27->32->1 via 32x32x16 bf16 MFMA (K=28->2x16).
// R21 = EXACT revert to R16, the measured best (17.91us). R20's float3+packed
// relu bundle regressed 2us (dwordx3 96B-stride loads beat the compiler's
// dwordx1x3 imm-offset coalescing). Ledger complete; this is the optimum.

#define NPTS  2097152
#define BLOCK 512
#define TILES 4
#define NBLK  (NPTS / (64 * (BLOCK / 64) * TILES))   // 1024

typedef __bf16 bf16x8 __attribute__((ext_vector_type(8)));
typedef __bf16 bf16x2 __attribute__((ext_vector_type(2)));
typedef float  f32x8  __attribute__((ext_vector_type(8)));
typedef float  f32x16 __attribute__((ext_vector_type(16)));
typedef float  f32x2  __attribute__((ext_vector_type(2)));
typedef unsigned int u32;
typedef u32 u32x4 __attribute__((ext_vector_type(4)));

__device__ __forceinline__ u32 pk_sc(float ang /*revolutions*/) {
    const float a = __builtin_amdgcn_fractf(ang);
    f32x2 sc;
    sc[0] = __builtin_amdgcn_sinf(a);
    sc[1] = __builtin_amdgcn_cosf(a);
    return __builtin_bit_cast(u32, __builtin_convertvector(sc, bf16x2));
}

__global__ __launch_bounds__(BLOCK, 4) void nerf_nolds(
    const float* __restrict__ x,
    const float* __restrict__ W1,
    const float* __restrict__ b1,
    const float* __restrict__ W2,
    const float* __restrict__ b2,
    float* __restrict__ out)
{
    const int tid  = threadIdx.x;
    const int wave = tid >> 6;
    const int lane = tid & 63;
    const int h    = lane >> 5;   // k-half: bands {h, 2+h}
    const int col  = lane & 31;   // point-in-group / hidden j (A operand)

    // per-lane band scales in revolutions
    const float INV2PI = 0.15915494309189535f;
    const float FgA = (h ? 10.0793684f : 1.0f)         * INV2PI;
    const float FgB = (h ? 1024.0f     : 101.5936673f) * INV2PI;
    const float bias2 = b2[0];
    const f32x16 Z = {};

    // ---- layer-1 A fragments gathered from GLOBAL (L1-resident weights) ----
    // k-order: MFMA1 i=2m sin_h(x_m) row 3+6h+m; i=2m+1 cos_h row 6+6h+m;
    //          i=6: h?x2:x0 (row 2|0); i=7: h?bias:x1 (b1|row 1).
    //          MFMA2 rows 15+6h+m / 18+6h+m; i=6,7 zero.
    bf16x8 af1, af2;
    {
        f32x8 t1, t2;
        #pragma unroll
        for (int m = 0; m < 3; ++m) {
            t1[2 * m]     = W1[(3  + 6 * h + m) * 32 + col];
            t1[2 * m + 1] = W1[(6  + 6 * h + m) * 32 + col];
            t2[2 * m]     = W1[(15 + 6 * h + m) * 32 + col];
            t2[2 * m + 1] = W1[(18 + 6 * h + m) * 32 + col];
        }
        t1[6] = h ? W1[2 * 32 + col] : W1[0 * 32 + col];
        t1[7] = h ? b1[col]          : W1[1 * 32 + col];   // bias | x1-row
        t2[6] = 0.0f; t2[7] = 0.0f;
        af1 = __builtin_convertvector(t1, bf16x8);
        af2 = __builtin_convertvector(t2, bf16x8);
    }
    // layer-2 weights for lane's 16 C/D rows (pairs for pk_fma)
    f32x2 w2p[8];
    #pragma unroll
    for (int m = 0; m < 8; ++m) {
        const int r0 = 8 * (m >> 1) + 4 * h + 2 * (m & 1);
        w2p[m][0] = W2[r0];
        w2p[m][1] = W2[r0 + 1];
    }

    const int tbase = blockIdx.x * ((BLOCK / 64) * TILES) + wave * TILES;
    const float* xb = x + (size_t)tbase * 192 + col * 3;   // my col's base
    float* ob = out + (size_t)tbase * 64 + lane;

    #pragma unroll
    for (int t = 0; t < TILES; ++t) {
        float S[2];
        #pragma unroll
        for (int gr = 0; gr < 2; ++gr) {
            // my point for this group: 64t + 32gr + col (imm offsets)
            const float x0 = xb[t * 192 + gr * 96 + 0];
            const float x1 = xb[t * 192 + gr * 96 + 1];
            const float x2 = xb[t * 192 + gr * 96 + 2];

            // 6 packed {sin,cos} pairs via trans pipe (bands h and 2+h)
            u32x4 u1, u2;
            u1[0] = pk_sc(x0 * FgA);
            u1[1] = pk_sc(x1 * FgA);
            u1[2] = pk_sc(x2 * FgA);
            f32x2 ex;
            ex[0] = h ? x2 : x0;
            ex[1] = h ? 1.0f : x1;     // bias multiplier lives in h=1
            u1[3] = __builtin_bit_cast(u32, __builtin_convertvector(ex, bf16x2));
            u2[0] = pk_sc(x0 * FgB);
            u2[1] = pk_sc(x1 * FgB);
            u2[2] = pk_sc(x2 * FgB);
            u2[3] = 0u;
            const bf16x8 B1 = __builtin_bit_cast(bf16x8, u1);
            const bf16x8 B2 = __builtin_bit_cast(bf16x8, u2);

            // layer 1: 2 chained 32x32x16 MFMAs -> 32 hidden x 32 points
            f32x16 acc = __builtin_amdgcn_mfma_f32_32x32x16_bf16(af1, B1, Z, 0, 0, 0);
            acc = __builtin_amdgcn_mfma_f32_32x32x16_bf16(af2, B2, acc, 0, 0, 0);

            // layer 2: relu + pk_fma over lane's 16 rows, fold halves
            f32x2 ps = {0.0f, 0.0f};
            #pragma unroll
            for (int m = 0; m < 8; ++m) {
                f32x2 v = {acc[2 * m], acc[2 * m + 1]};
                f32x2 zz = {0.f, 0.f};
                v = __builtin_elementwise_max(v, zz);
                ps = ps + v * w2p[m];
            }
            float s = ps[0] + ps[1];
            s += __shfl_xor(s, 32, 64);   // combine k-halves
            S[gr] = s;
        }
        // lane (h,col) stores point 32h+col of the tile
        const float v = h ? S[1] : S[0];
        ob[t * 64] = fmaxf(v + bias2, 0.0f);
    }
}

extern "C" void kernel_launch(void* const* d_in, const int* in_sizes, int n_in,
                              void* d_out, int out_size, void* d_ws, size_t ws_size,
                              hipStream_t stream) {
    const float* x  = (const float*)d_in[0];
    const float* W1 = (const float*)d_in[1];
    const float* b1 = (const float*)d_in[2];
    const float* W2 = (const float*)d_in[3];
    const float* b2 = (const float*)d_in[4];
    float* out = (float*)d_out;

    nerf_nolds<<<NBLK, BLOCK, 0, stream>>>(x, W1, b1, W2, b2, out);
}